// Round 5
// baseline (272.283 us; speedup 1.0000x reference)
//
#include <hip/hip_runtime.h>
#include <math.h>

// Problem constants
#define M_TOKENS 16384               // B*S = 4*4096
#define E_EXPERTS 64
#define K_DIM 2048
#define KSPLIT 4
#define KCHUNK (K_DIM / KSPLIT)      // 512
#define PSTRIDE (KSPLIT * E_EXPERTS) // 256 floats per token in partials
#define TPB 128                      // tokens per block
#define SK 32                        // k-depth per LDS stage
#define NS (KCHUNK / SK)             // 16 stages
#define EPW 32                       // experts per wave (ESPLIT=2)

// ---------------------------------------------------------------------------
// Gates kernel — lane=token compute (proven round 1/3 dataflow) with the x
// feed moved to LDS:
//  - W stays wave-uniform -> compiler promotes to s_load broadcast (cheap,
//    sequential shared stream; scalar-cache friendly, unlike round 4's x).
//  - x staged per 128-token x 32-k tile: global loads coalesced (8 lanes/row
//    float4), stored TRANSPOSED xT[k][128+1]. 129 = 1 mod 32 -> both the
//    transpose ds_writes and the compute ds_read (64 consecutive tokens)
//    are <=2 lanes/bank = free (m136). One ds_read_b32 per k per lane
//    replaces round 3's 64-lines-per-instruction global loads.
//  - Double-buffered LDS, ONE barrier per stage; next-stage global->reg
//    loads issued before the barrier (round-4 structure, race-free).
//  - FMA chain per (token, expert, kc) is k-ascending over the 512-chunk,
//    KSPLIT=4, reduce order unchanged -> bit-identical to rounds 1/3.
// ---------------------------------------------------------------------------
__global__ __launch_bounds__(256) void gates_kernel(
    const float* __restrict__ x, const float* __restrict__ W,
    float* __restrict__ part) {
  __shared__ float xT[2][SK][TPB + 1];   // 2 x 16.5 KB -> 4 blocks/CU

  const int tid = threadIdx.x;
  const int lane = tid & 63;
  const int w = tid >> 6;
  const int th = w & 1;                  // token half
  const int eh = w >> 1;                 // expert half (0..1)
  const int tg = blockIdx.x >> 2;
  const int kc = blockIdx.x & 3;
  const int kbase = kc * KCHUNK;
  const int tok0 = tg * TPB;
  const int mytok = th * 64 + lane;      // 0..127

  const float* wb0 = W + (size_t)kbase * E_EXPERTS + eh * EPW;

  float acc[EPW];
#pragma unroll
  for (int e = 0; e < EPW; ++e) acc[e] = 0.0f;

  float4 stg[4];

  // stage tile = 128 rows x 32 floats = 1024 float4; thread covers 4:
  // f = tid + 256*j; row = f>>3 (8 f4/row), c4 = f&7. 8 consecutive lanes
  // read one contiguous 128B row chunk -> 16 lines per wave instruction.
#define LOADS(s)                                                              \
  do {                                                                        \
    const float* src = x + (size_t)tok0 * K_DIM + kbase + (s) * SK;           \
    _Pragma("unroll") for (int j = 0; j < 4; ++j) {                           \
      int f = tid + 256 * j;                                                  \
      int row = f >> 3, c4 = f & 7;                                           \
      stg[j] = *reinterpret_cast<const float4*>(src + (size_t)row * K_DIM +   \
                                                c4 * 4);                      \
    }                                                                         \
  } while (0)

#define WRITES(s)                                                             \
  do {                                                                        \
    float* dst = &xT[(s) & 1][0][0];                                          \
    _Pragma("unroll") for (int j = 0; j < 4; ++j) {                           \
      int f = tid + 256 * j;                                                  \
      int row = f >> 3, c4 = f & 7;                                           \
      dst[(c4 * 4 + 0) * (TPB + 1) + row] = stg[j].x;                         \
      dst[(c4 * 4 + 1) * (TPB + 1) + row] = stg[j].y;                         \
      dst[(c4 * 4 + 2) * (TPB + 1) + row] = stg[j].z;                         \
      dst[(c4 * 4 + 3) * (TPB + 1) + row] = stg[j].w;                         \
    }                                                                         \
  } while (0)

  LOADS(0);
  WRITES(0);

  for (int s = 0; s < NS; ++s) {
    if (s + 1 < NS) LOADS(s + 1);   // global->reg, overlaps barrier+compute
    __syncthreads();                // stage s transpose visible everywhere

    const float* wk = wb0 + (size_t)s * SK * E_EXPERTS;
    const float* xb = &xT[s & 1][0][0];
#pragma unroll 8
    for (int k = 0; k < SK; ++k) {
      float xk = xb[k * (TPB + 1) + mytok];
#pragma unroll
      for (int e = 0; e < EPW; ++e)
        acc[e] = fmaf(xk, wk[k * E_EXPERTS + e], acc[e]);
    }

    if (s + 1 < NS) WRITES(s + 1);  // other buffer; race-free (see header)
  }
#undef LOADS
#undef WRITES

  // epilogue: 8 float4 stores, contiguous 32 floats per lane
  float* p = part + (size_t)(tok0 + mytok) * PSTRIDE + kc * E_EXPERTS +
             eh * EPW;
#pragma unroll
  for (int v = 0; v < EPW / 4; ++v) {
    *reinterpret_cast<float4*>(p + v * 4) =
        make_float4(acc[4 * v + 0], acc[4 * v + 1], acc[4 * v + 2],
                    acc[4 * v + 3]);
  }
}

// ---------------------------------------------------------------------------
// Reduce + bias + top-2 + softmax (unchanged from round 3 — passed exact).
// ---------------------------------------------------------------------------
__global__ __launch_bounds__(64) void reduce_topk_kernel(
    const float* __restrict__ part, const float* __restrict__ bias,
    float* __restrict__ out) {
  const int t = blockIdx.x * 64 + threadIdx.x;
  const float4* p = reinterpret_cast<const float4*>(part + (size_t)t * PSTRIDE);
  const float4* b4 = reinterpret_cast<const float4*>(bias);

  float m1 = -INFINITY, m2 = -INFINITY;
  int i1 = 0, i2 = 0;

#pragma unroll 4
  for (int e4 = 0; e4 < 16; ++e4) {
    float4 a = p[e4];        // kc = 0
    float4 b = p[16 + e4];   // kc = 1
    float4 c = p[32 + e4];   // kc = 2
    float4 d = p[48 + e4];   // kc = 3
    float4 bb = b4[e4];
    float g[4];
    g[0] = bb.x + a.x; g[0] += b.x; g[0] += c.x; g[0] += d.x;
    g[1] = bb.y + a.y; g[1] += b.y; g[1] += c.y; g[1] += d.y;
    g[2] = bb.z + a.z; g[2] += b.z; g[2] += c.z; g[2] += d.z;
    g[3] = bb.w + a.w; g[3] += b.w; g[3] += c.w; g[3] += d.w;
#pragma unroll
    for (int j = 0; j < 4; ++j) {
      int e = e4 * 4 + j;
      if (g[j] > m1) {
        m2 = m1; i2 = i1;
        m1 = g[j]; i1 = e;
      } else if (g[j] > m2) {
        m2 = g[j]; i2 = e;
      }
    }
  }

  float w0 = 1.0f / (1.0f + expf(m2 - m1));
  out[2 * t + 0] = w0;
  out[2 * t + 1] = 1.0f - w0;
  float* oidx = out + 2 * (size_t)M_TOKENS;
  oidx[2 * t + 0] = (float)i1;
  oidx[2 * t + 1] = (float)i2;
}

// ---------------------------------------------------------------------------
// Fallback (proven correct in round 1): fully fused, no workspace.
// ---------------------------------------------------------------------------
__global__ __launch_bounds__(64) void router_fused_kernel(
    const float* __restrict__ x, const float* __restrict__ W,
    const float* __restrict__ bias, float* __restrict__ out) {
  const int t = blockIdx.x * 64 + threadIdx.x;
  const float* xrow = x + (size_t)t * K_DIM;

  float acc[E_EXPERTS];
#pragma unroll
  for (int e = 0; e < E_EXPERTS; ++e) acc[e] = 0.0f;

  for (int k4 = 0; k4 < K_DIM; k4 += 4) {
    float4 xv = *reinterpret_cast<const float4*>(xrow + k4);
    float xs[4] = {xv.x, xv.y, xv.z, xv.w};
#pragma unroll
    for (int kk = 0; kk < 4; ++kk) {
      const float* wrow = W + (size_t)(k4 + kk) * E_EXPERTS;
#pragma unroll
      for (int e = 0; e < E_EXPERTS; ++e) acc[e] = fmaf(xs[kk], wrow[e], acc[e]);
    }
  }

  float m1 = -INFINITY, m2 = -INFINITY;
  int i1 = 0, i2 = 0;
#pragma unroll
  for (int e = 0; e < E_EXPERTS; ++e) {
    float g = acc[e] + bias[e];
    if (g > m1) {
      m2 = m1; i2 = i1;
      m1 = g; i1 = e;
    } else if (g > m2) {
      m2 = g; i2 = e;
    }
  }

  float w0 = 1.0f / (1.0f + expf(m2 - m1));
  out[2 * t + 0] = w0;
  out[2 * t + 1] = 1.0f - w0;
  float* oidx = out + 2 * (size_t)M_TOKENS;
  oidx[2 * t + 0] = (float)i1;
  oidx[2 * t + 1] = (float)i2;
}

extern "C" void kernel_launch(void* const* d_in, const int* in_sizes, int n_in,
                              void* d_out, int out_size, void* d_ws, size_t ws_size,
                              hipStream_t stream) {
  const float* x = (const float*)d_in[0];
  const float* W = (const float*)d_in[1];
  const float* b = (const float*)d_in[2];
  float* out = (float*)d_out;

  const size_t need = (size_t)M_TOKENS * PSTRIDE * sizeof(float);
  if (ws_size >= need) {
    float* part = (float*)d_ws;
    gates_kernel<<<(M_TOKENS / TPB) * KSPLIT, 256, 0, stream>>>(x, W, part);
    reduce_topk_kernel<<<M_TOKENS / 64, 64, 0, stream>>>(part, b, out);
  } else {
    router_fused_kernel<<<M_TOKENS / 64, 64, 0, stream>>>(x, W, b, out);
  }
}

// Round 6
// 91.579 us; speedup vs baseline: 2.9732x; 2.9732x over previous
//
#include <hip/hip_runtime.h>
#include <math.h>

// Problem constants
#define M_TOKENS 16384               // B*S = 4*4096
#define E_EXPERTS 64
#define K_DIM 2048
#define KSPLIT 4
#define KCHUNK (K_DIM / KSPLIT)      // 512
#define ESPLIT 2
#define EPW (E_EXPERTS / ESPLIT)     // 32 experts per wave
#define PSTRIDE (KSPLIT * E_EXPERTS) // 256 floats per token in partials

// ---------------------------------------------------------------------------
// Gates kernel — round-3 dataflow (lane=token, W wave-uniform scalar loads,
// x per-lane VMEM, zero LDS) with EPW doubled 16->32:
//  - each x float4 now feeds 128 FMAs (256 VALU cyc) -> line-touch rate
//    halves to 0.25 lines/cyc/wave (round 3's measured limiter).
//  - block = 128 thr = 2 waves (expert halves) on the SAME 64 tokens ->
//    second wave's x stream is an L1 hit. 1024 blocks = 4/CU = 8 waves/CU.
//  - 4-deep float4 rotation prefetch, >=384 FMA instrs between load & use.
//  - FMA chain per (token, expert, kc): k-ascending, KSPLIT=4, reduce order
//    unchanged -> summation order bit-identical to rounds 1/3 (absmax 0).
// ---------------------------------------------------------------------------
__global__ __launch_bounds__(128) void gates_kernel(
    const float* __restrict__ x, const float* __restrict__ W,
    float* __restrict__ part) {
  const int tid = threadIdx.x;
  const int lane = tid & 63;
  const int eh = __builtin_amdgcn_readfirstlane(tid >> 6);  // expert half
  const int tg = blockIdx.x >> 2;
  const int kc = blockIdx.x & 3;
  const int t = tg * 64 + lane;
  const int kbase = kc * KCHUNK;

  const float* xp = x + (size_t)t * K_DIM + kbase;
  const float* wp = W + (size_t)kbase * E_EXPERTS + eh * EPW;

  float acc[EPW];
#pragma unroll
  for (int e = 0; e < EPW; ++e) acc[e] = 0.0f;

  float4 b0 = *reinterpret_cast<const float4*>(xp + 0);
  float4 b1 = *reinterpret_cast<const float4*>(xp + 4);
  float4 b2 = *reinterpret_cast<const float4*>(xp + 8);
  float4 b3 = *reinterpret_cast<const float4*>(xp + 12);

#define FMA4(bv, kofs)                                                        \
  do {                                                                        \
    const float* wr0 = wp + (size_t)(kofs)*E_EXPERTS;                         \
    float xs[4] = {bv.x, bv.y, bv.z, bv.w};                                   \
    _Pragma("unroll") for (int kk = 0; kk < 4; ++kk) {                        \
      const float* wr = wr0 + kk * E_EXPERTS;                                 \
      _Pragma("unroll") for (int e = 0; e < EPW; ++e)                         \
        acc[e] = fmaf(xs[kk], wr[e], acc[e]);                                 \
    }                                                                         \
  } while (0)

  // 512 k = 32 groups of 16; last group peeled (no prefetch -> no OOB reads)
  for (int g = 0; g < KCHUNK / 16 - 1; ++g) {
    const int k0 = g * 16;
    FMA4(b0, k0 + 0);  b0 = *reinterpret_cast<const float4*>(xp + k0 + 16);
    FMA4(b1, k0 + 4);  b1 = *reinterpret_cast<const float4*>(xp + k0 + 20);
    FMA4(b2, k0 + 8);  b2 = *reinterpret_cast<const float4*>(xp + k0 + 24);
    FMA4(b3, k0 + 12); b3 = *reinterpret_cast<const float4*>(xp + k0 + 28);
  }
  {
    const int k0 = KCHUNK - 16;
    FMA4(b0, k0 + 0);
    FMA4(b1, k0 + 4);
    FMA4(b2, k0 + 8);
    FMA4(b3, k0 + 12);
  }
#undef FMA4

  // epilogue: 8 float4 stores, contiguous 32 floats per lane
  float* p = part + (size_t)t * PSTRIDE + kc * E_EXPERTS + eh * EPW;
#pragma unroll
  for (int v = 0; v < EPW / 4; ++v) {
    *reinterpret_cast<float4*>(p + v * 4) =
        make_float4(acc[4 * v + 0], acc[4 * v + 1], acc[4 * v + 2],
                    acc[4 * v + 3]);
  }
}

// ---------------------------------------------------------------------------
// Reduce + bias + top-2 + softmax (unchanged from round 3 — passed exact).
// ---------------------------------------------------------------------------
__global__ __launch_bounds__(64) void reduce_topk_kernel(
    const float* __restrict__ part, const float* __restrict__ bias,
    float* __restrict__ out) {
  const int t = blockIdx.x * 64 + threadIdx.x;
  const float4* p = reinterpret_cast<const float4*>(part + (size_t)t * PSTRIDE);
  const float4* b4 = reinterpret_cast<const float4*>(bias);

  float m1 = -INFINITY, m2 = -INFINITY;
  int i1 = 0, i2 = 0;

#pragma unroll 4
  for (int e4 = 0; e4 < 16; ++e4) {
    float4 a = p[e4];        // kc = 0
    float4 b = p[16 + e4];   // kc = 1
    float4 c = p[32 + e4];   // kc = 2
    float4 d = p[48 + e4];   // kc = 3
    float4 bb = b4[e4];
    float g[4];
    g[0] = bb.x + a.x; g[0] += b.x; g[0] += c.x; g[0] += d.x;
    g[1] = bb.y + a.y; g[1] += b.y; g[1] += c.y; g[1] += d.y;
    g[2] = bb.z + a.z; g[2] += b.z; g[2] += c.z; g[2] += d.z;
    g[3] = bb.w + a.w; g[3] += b.w; g[3] += c.w; g[3] += d.w;
#pragma unroll
    for (int j = 0; j < 4; ++j) {
      int e = e4 * 4 + j;
      if (g[j] > m1) {
        m2 = m1; i2 = i1;
        m1 = g[j]; i1 = e;
      } else if (g[j] > m2) {
        m2 = g[j]; i2 = e;
      }
    }
  }

  float w0 = 1.0f / (1.0f + expf(m2 - m1));
  out[2 * t + 0] = w0;
  out[2 * t + 1] = 1.0f - w0;
  float* oidx = out + 2 * (size_t)M_TOKENS;
  oidx[2 * t + 0] = (float)i1;
  oidx[2 * t + 1] = (float)i2;
}

// ---------------------------------------------------------------------------
// Fallback (proven correct in round 1): fully fused, no workspace.
// ---------------------------------------------------------------------------
__global__ __launch_bounds__(64) void router_fused_kernel(
    const float* __restrict__ x, const float* __restrict__ W,
    const float* __restrict__ bias, float* __restrict__ out) {
  const int t = blockIdx.x * 64 + threadIdx.x;
  const float* xrow = x + (size_t)t * K_DIM;

  float acc[E_EXPERTS];
#pragma unroll
  for (int e = 0; e < E_EXPERTS; ++e) acc[e] = 0.0f;

  for (int k4 = 0; k4 < K_DIM; k4 += 4) {
    float4 xv = *reinterpret_cast<const float4*>(xrow + k4);
    float xs[4] = {xv.x, xv.y, xv.z, xv.w};
#pragma unroll
    for (int kk = 0; kk < 4; ++kk) {
      const float* wrow = W + (size_t)(k4 + kk) * E_EXPERTS;
#pragma unroll
      for (int e = 0; e < E_EXPERTS; ++e) acc[e] = fmaf(xs[kk], wrow[e], acc[e]);
    }
  }

  float m1 = -INFINITY, m2 = -INFINITY;
  int i1 = 0, i2 = 0;
#pragma unroll
  for (int e = 0; e < E_EXPERTS; ++e) {
    float g = acc[e] + bias[e];
    if (g > m1) {
      m2 = m1; i2 = i1;
      m1 = g; i1 = e;
    } else if (g > m2) {
      m2 = g; i2 = e;
    }
  }

  float w0 = 1.0f / (1.0f + expf(m2 - m1));
  out[2 * t + 0] = w0;
  out[2 * t + 1] = 1.0f - w0;
  float* oidx = out + 2 * (size_t)M_TOKENS;
  oidx[2 * t + 0] = (float)i1;
  oidx[2 * t + 1] = (float)i2;
}

extern "C" void kernel_launch(void* const* d_in, const int* in_sizes, int n_in,
                              void* d_out, int out_size, void* d_ws, size_t ws_size,
                              hipStream_t stream) {
  const float* x = (const float*)d_in[0];
  const float* W = (const float*)d_in[1];
  const float* b = (const float*)d_in[2];
  float* out = (float*)d_out;

  const size_t need = (size_t)M_TOKENS * PSTRIDE * sizeof(float);
  if (ws_size >= need) {
    float* part = (float*)d_ws;
    gates_kernel<<<(M_TOKENS / 64) * KSPLIT, 128, 0, stream>>>(x, W, part);
    reduce_topk_kernel<<<M_TOKENS / 64, 64, 0, stream>>>(part, b, out);
  } else {
    router_fused_kernel<<<M_TOKENS / 64, 64, 0, stream>>>(x, W, b, out);
  }
}